// Round 1
// baseline (949.110 us; speedup 1.0000x reference)
//
#include <hip/hip_runtime.h>
#include <hip/hip_bf16.h>

typedef unsigned short ushort_t;
typedef __attribute__((ext_vector_type(4))) float f32x4;
typedef __attribute__((ext_vector_type(8))) short short8;
typedef __attribute__((ext_vector_type(4))) unsigned short u16x4;
typedef __attribute__((ext_vector_type(8))) unsigned short u16x8;
typedef __attribute__((ext_vector_type(4))) int i32x4;

// Problem sizes (fixed by the reference): B=4, S=2048, I=4096, O=4096
constexpr int Mdim = 8192;   // B*S
constexpr int Ndim = 4096;   // O
constexpr int Kdim = 4096;   // I
constexpr int BM = 128, BN = 128, BK = 32;

// round-to-nearest-even f32 -> bf16 (inputs are finite; no NaN handling needed)
__device__ __forceinline__ ushort_t f2bf(float f) {
  unsigned u = __float_as_uint(f);
  u += 0x7fffu + ((u >> 16) & 1u);
  return (ushort_t)(u >> 16);
}

// gumbel = -log(max(-log(max(1-u,1e-12)),1e-10)); accurate logf to track the
// reference's argmax as closely as possible (near-ties are the correctness risk)
__device__ __forceinline__ float gumbel_from_u(float u) {
  float e = -logf(fmaxf(1.0f - u, 1e-12f));
  return -logf(fmaxf(e, 1e-10f));
}

// ---------------- Phase 1: ternary weight generation -> bf16 W[N][K] ----------
__global__ __launch_bounds__(256) void wgen_kernel(
    const f32x4* __restrict__ lg, const f32x4* __restrict__ uu,
    const float* __restrict__ scales, const i32x4* __restrict__ mask4,
    ushort_t* __restrict__ W) {
  int t = blockIdx.x * 256 + threadIdx.x;     // each thread: 4 consecutive (o,i)
  f32x4 L0 = lg[t * 3 + 0], L1 = lg[t * 3 + 1], L2 = lg[t * 3 + 2];
  f32x4 U0 = uu[t * 3 + 0], U1 = uu[t * 3 + 1], U2 = uu[t * 3 + 2];
  i32x4 mk = mask4[t];
  int idx = t << 2;
  int i = idx & (Kdim - 1);
  int o = idx >> 12;                          // Kdim = 2^12
  float sc = scales[(o << 5) | (i >> 7)];     // 32 groups of 128 per row

  float lf[12], uf[12];
#pragma unroll
  for (int r = 0; r < 4; r++) { lf[r] = L0[r]; lf[4 + r] = L1[r]; lf[8 + r] = L2[r];
                                uf[r] = U0[r]; uf[4 + r] = U1[r]; uf[8 + r] = U2[r]; }
  u16x4 outv;
#pragma unroll
  for (int j = 0; j < 4; j++) {
    float s0 = lf[3 * j + 0] + gumbel_from_u(uf[3 * j + 0]);
    float s1 = lf[3 * j + 1] + gumbel_from_u(uf[3 * j + 1]);
    float s2 = lf[3 * j + 2] + gumbel_from_u(uf[3 * j + 2]);
    // jnp.argmax picks FIRST max -> strict > keeps earlier index on ties
    int a = 0; float b = s0;
    if (s1 > b) { b = s1; a = 1; }
    if (s2 > b) { b = s2; a = 2; }
    float wv = (a == 2) ? sc : ((a == 0) ? -sc : 0.0f);
    wv = mk[j] ? wv : 0.0f;
    outv[j] = f2bf(wv);
  }
  *reinterpret_cast<u16x4*>(W + idx) = outv;  // 8B store, aligned
}

// ---------------- Phase 2: x f32 -> bf16 ---------------------------------------
__global__ __launch_bounds__(256) void xconv_kernel(
    const f32x4* __restrict__ x, u16x8* __restrict__ xb) {
  int t = blockIdx.x * 256 + threadIdx.x;     // 8 floats per thread
  f32x4 v0 = x[t * 2], v1 = x[t * 2 + 1];
  u16x8 p;
#pragma unroll
  for (int j = 0; j < 4; j++) { p[j] = f2bf(v0[j]); p[4 + j] = f2bf(v1[j]); }
  xb[t] = p;
}

// ---------------- Phase 3: bf16 GEMM (m97 structure) ---------------------------
// out[m][n] = sum_k A[m][k] * W[n][k]   (A row-major MxK, W row-major NxK = B^T)
#define GLOAD16(gp, lp)                                           \
  __builtin_amdgcn_global_load_lds(                               \
      (const __attribute__((address_space(1))) void*)(gp),        \
      (__attribute__((address_space(3))) void*)(lp), 16, 0, 0)

template <int AF32>
__global__ __launch_bounds__(256) void gemm_kernel(
    const ushort_t* __restrict__ Abf, const float* __restrict__ Af,
    const ushort_t* __restrict__ Bw, float* __restrict__ C) {
  __shared__ ushort_t As[BM * BK];   // [128][32] bf16, row stride 64B
  __shared__ ushort_t Bs[BN * BK];

  const int tid = threadIdx.x;
  const int w = tid >> 6, l = tid & 63;

  // XCD-aware swizzle (2048 % 8 == 0 -> bijective contiguous chunks)
  int bid = blockIdx.x;
  const int nwg = gridDim.x;
  if ((nwg & 7) == 0) { const int cpx = nwg >> 3; bid = (bid & 7) * cpx + (bid >> 3); }
  const int tn = bid & (Ndim / BN - 1);
  const int tm = bid >> 5;                    // Ndim/BN = 32 tiles

  const int wr = w >> 1, wc = w & 1;          // 2x2 wave grid, 64x64 per wave
  const int fr = l & 15, fq = l >> 4;         // MFMA fragment coords

  f32x4 acc[4][4] = {};

  const int arow = w * 16 + (l >> 2);         // staging row within 16-row chunk
  const int acol = (l & 3) * 8;               // 8 bf16 = 16B per lane
  const long abase = (long)(tm * BM) * Kdim;
  const long bbase = (long)(tn * BN) * Kdim;

  for (int kk = 0; kk < Kdim; kk += BK) {
    if constexpr (!AF32) {
#pragma unroll
      for (int s = 0; s < 2; s++) {
        const ushort_t* ga = Abf + abase + (long)(s * 64 + arow) * Kdim + kk + acol;
        GLOAD16(ga, &As[(s * 64 + w * 16) * BK]);
        const ushort_t* gb = Bw + bbase + (long)(s * 64 + arow) * Kdim + kk + acol;
        GLOAD16(gb, &Bs[(s * 64 + w * 16) * BK]);
      }
    } else {
      // B via async LDS load; A reg-staged from f32 with on-the-fly bf16 convert
#pragma unroll
      for (int s = 0; s < 2; s++) {
        const ushort_t* gb = Bw + bbase + (long)(s * 64 + arow) * Kdim + kk + acol;
        GLOAD16(gb, &Bs[(s * 64 + w * 16) * BK]);
      }
#pragma unroll
      for (int s = 0; s < 2; s++) {
        const int r2 = s * 64 + (tid >> 2);
        const int c2 = (tid & 3) * 8;
        const float* gx = Af + abase + (long)r2 * Kdim + kk + c2;
        f32x4 v0 = *reinterpret_cast<const f32x4*>(gx);
        f32x4 v1 = *reinterpret_cast<const f32x4*>(gx + 4);
        u16x8 pk;
#pragma unroll
        for (int j = 0; j < 4; j++) { pk[j] = f2bf(v0[j]); pk[4 + j] = f2bf(v1[j]); }
        *reinterpret_cast<u16x8*>(&As[r2 * BK + c2]) = pk;
      }
    }
    __syncthreads();

    short8 af[4], bfr[4];
#pragma unroll
    for (int i = 0; i < 4; i++)
      af[i] = *reinterpret_cast<const short8*>(&As[(wr * 64 + i * 16 + fr) * BK + fq * 8]);
#pragma unroll
    for (int i = 0; i < 4; i++)
      bfr[i] = *reinterpret_cast<const short8*>(&Bs[(wc * 64 + i * 16 + fr) * BK + fq * 8]);
#pragma unroll
    for (int i = 0; i < 4; i++)
#pragma unroll
      for (int j = 0; j < 4; j++)
        acc[i][j] = __builtin_amdgcn_mfma_f32_16x16x32_bf16(af[i], bfr[j], acc[i][j], 0, 0, 0);
    __syncthreads();
  }

  // epilogue: C/D layout col=lane&15, row=(lane>>4)*4+reg (verified m89/m91)
  const long crow = (long)(tm * BM + wr * 64);
  const int ccol = tn * BN + wc * 64;
#pragma unroll
  for (int i = 0; i < 4; i++)
#pragma unroll
    for (int j = 0; j < 4; j++)
#pragma unroll
      for (int r = 0; r < 4; r++)
        C[(crow + i * 16 + fq * 4 + r) * (long)Ndim + ccol + j * 16 + fr] = acc[i][j][r];
}

extern "C" void kernel_launch(void* const* d_in, const int* in_sizes, int n_in,
                              void* d_out, int out_size, void* d_ws, size_t ws_size,
                              hipStream_t stream) {
  const float* x      = (const float*)d_in[0];
  const float* logits = (const float*)d_in[1];
  const float* u      = (const float*)d_in[2];
  const float* scales = (const float*)d_in[3];
  const int*   mask   = (const int*)d_in[4];
  float* out = (float*)d_out;

  ushort_t* W = (ushort_t*)d_ws;                       // [N][K] bf16, 32 MB
  const size_t wbytes = (size_t)Ndim * Kdim * 2;
  const size_t xbytes = (size_t)Mdim * Kdim * 2;

  // Phase 1: weight gen  (N*K/4 threads)
  wgen_kernel<<<(Ndim * (long)Kdim / 4) / 256, 256, 0, stream>>>(
      (const f32x4*)logits, (const f32x4*)u, scales, (const i32x4*)mask, W);

  const int gblocks = (Mdim / BM) * (Ndim / BN);       // 2048
  if (ws_size >= wbytes + xbytes) {
    ushort_t* xb = (ushort_t*)((char*)d_ws + wbytes);  // [M][K] bf16, 64 MB
    xconv_kernel<<<(Mdim * (long)Kdim / 8) / 256, 256, 0, stream>>>(
        (const f32x4*)x, (u16x8*)xb);
    gemm_kernel<0><<<gblocks, 256, 0, stream>>>(xb, nullptr, W, out);
  } else {
    gemm_kernel<1><<<gblocks, 256, 0, stream>>>(nullptr, x, W, out);
  }
}

// Round 2
// 794.129 us; speedup vs baseline: 1.1952x; 1.1952x over previous
//
#include <hip/hip_runtime.h>
#include <hip/hip_bf16.h>

typedef unsigned short ushort_t;
typedef __attribute__((ext_vector_type(4))) float f32x4;
typedef __attribute__((ext_vector_type(8))) short short8;
typedef __attribute__((ext_vector_type(4))) unsigned short u16x4;
typedef __attribute__((ext_vector_type(8))) unsigned short u16x8;
typedef __attribute__((ext_vector_type(4))) int i32x4;

constexpr int Mdim = 8192;   // B*S
constexpr int Ndim = 4096;   // O
constexpr int Kdim = 4096;   // I

__device__ __forceinline__ ushort_t f2bf(float f) {
  unsigned u = __float_as_uint(f);
  u += 0x7fffu + ((u >> 16) & 1u);
  return (ushort_t)(u >> 16);
}

__device__ __forceinline__ float gumbel_from_u(float u) {
  float e = -logf(fmaxf(1.0f - u, 1e-12f));
  return -logf(fmaxf(e, 1e-10f));
}

// ---------------- Phase 1: ternary weight generation -> bf16 W[N][K] ----------
// Coalesced: block stages 1024 (o,i) positions' logits/u (12KB each) via f32x4.
__global__ __launch_bounds__(256) void wgen_kernel(
    const float* __restrict__ lg, const float* __restrict__ uu,
    const float* __restrict__ scales, const i32x4* __restrict__ mask4,
    ushort_t* __restrict__ W) {
  __shared__ float ls[3072];
  __shared__ float us_[3072];
  const int tid = threadIdx.x;
  const f32x4* gl = (const f32x4*)lg + (size_t)blockIdx.x * 768;
  const f32x4* gu = (const f32x4*)uu + (size_t)blockIdx.x * 768;
#pragma unroll
  for (int w = 0; w < 3; w++) {
    ((f32x4*)ls)[w * 256 + tid]  = gl[w * 256 + tid];
    ((f32x4*)us_)[w * 256 + tid] = gu[w * 256 + tid];
  }
  i32x4 mk = mask4[(size_t)blockIdx.x * 256 + tid];
  __syncthreads();
  const long idx = (long)blockIdx.x * 1024 + tid * 4;
  const int i = (int)(idx & (Kdim - 1));
  const int o = (int)(idx >> 12);
  const float sc = scales[(o << 5) | (i >> 7)];
  u16x4 outv;
#pragma unroll
  for (int j = 0; j < 4; j++) {
    const float* lp = &ls[tid * 12 + j * 3];
    const float* up = &us_[tid * 12 + j * 3];
    float s0 = lp[0] + gumbel_from_u(up[0]);
    float s1 = lp[1] + gumbel_from_u(up[1]);
    float s2 = lp[2] + gumbel_from_u(up[2]);
    int a = 0; float b = s0;               // argmax picks FIRST max
    if (s1 > b) { b = s1; a = 1; }
    if (s2 > b) { b = s2; a = 2; }
    float wv = (a == 2) ? sc : ((a == 0) ? -sc : 0.0f);
    wv = mk[j] ? wv : 0.0f;
    outv[j] = f2bf(wv);
  }
  *reinterpret_cast<u16x4*>(W + idx) = outv;
}

// ---------------- Phase 2: x f32 -> bf16 (coalesced dual-stream) ---------------
__global__ __launch_bounds__(256) void xconv_kernel(
    const f32x4* __restrict__ x, u16x4* __restrict__ xb) {
  const size_t base = (size_t)blockIdx.x * 512;
  const int tid = threadIdx.x;
  f32x4 v0 = x[base + tid], v1 = x[base + 256 + tid];
  u16x4 p0, p1;
#pragma unroll
  for (int j = 0; j < 4; j++) { p0[j] = f2bf(v0[j]); p1[j] = f2bf(v1[j]); }
  xb[base + tid] = p0;
  xb[base + 256 + tid] = p1;
}

// ---------------- Phase 3: 256x256 8-phase bf16 GEMM ---------------------------
// out[m][n] = sum_k A[m][k] * W[n][k]; A [M][K] bf16, W [N][K] bf16 (B^T form)
#define GLOAD16(gp, lp)                                           \
  __builtin_amdgcn_global_load_lds(                               \
      (const __attribute__((address_space(1))) void*)(gp),        \
      (__attribute__((address_space(3))) void*)(lp), 16, 0, 0)

// LDS: 8 slots x 16KB. Slot (j&7) holds half-tile H_j:
//   j&3: 0=A[256][k 0:32], 1=B[256][k 0:32], 2=A[256][k 32:64], 3=B[256][k 32:64]
//   (k offsets within K-tile j>>2; buffer = (j>>2)&1)
// Swizzle: byte ^= ((byte>>6)&3)<<4 (XOR 16B-chunk idx with row bits, 64B rows).
// Schedule: stage-ahead 5 halves; vmcnt(6) after phases p1,p3 only (3 halves in
// flight). Derivation: H_j issued at G=j-5; after odd-phase wait, landed through
// H_{G+2}; first reads: H_{4t},H_{4t+1}@G=4t, H_{4t+2},H_{4t+3}@G=4t+2 -> all
// covered. Overwrite of H_j by H_{j+8} issues at G=j+3 > last read of H_j. Tail
// waits: t=62/p3 -> vmcnt(4), t=63/p1 -> vmcnt(0).
__global__ __launch_bounds__(512, 2) void gemm8_kernel(
    const ushort_t* __restrict__ Abf, const ushort_t* __restrict__ Bw,
    float* __restrict__ C) {
  __shared__ char lds[131072];

  const int tid = threadIdx.x;
  const int wv = tid >> 6, l = tid & 63;
  const int fr = l & 15, fq = l >> 4;
  const int wr = wv >> 2, wc = wv & 3;      // 2(M) x 4(N) wave grid, 128x64/wave

  int bid = blockIdx.x;                     // 512 blocks = 8 * 64 -> bijective
  bid = (bid & 7) * 64 + (bid >> 3);        // XCD swizzle
  const int tn = bid & 15, tm = bid >> 4;

  // Per-thread staging source bases (2 sweeps of 512x16B per half-tile).
  // Linear LDS dest chunk q -> logical a=swz(q) -> global (row a>>6, byte a&63).
  const char* baseA[2];
  const char* baseB[2];
#pragma unroll
  for (int w = 0; w < 2; w++) {
    int q = (w * 512 + tid) * 16;
    int a = q ^ (((q >> 6) & 3) << 4);
    int r = a >> 6, cb = a & 63;
    baseA[w] = (const char*)Abf + (size_t)(tm * 256 + r) * (Kdim * 2) + cb;
    baseB[w] = (const char*)Bw  + (size_t)(tn * 256 + r) * (Kdim * 2) + cb;
  }
  const int wvoff = wv * 1024;

  auto stage_j = [&](int j) {
    int s = j & 3;
    int colb = (j >> 2) * 128 + ((s >> 1) << 6);   // byte offset within row
    int o0 = __builtin_amdgcn_readfirstlane((j & 7) * 16384 + wvoff);
    const char* b0 = (s & 1) ? baseB[0] : baseA[0];
    const char* b1 = (s & 1) ? baseB[1] : baseA[1];
    GLOAD16(b0 + colb, lds + o0);
    GLOAD16(b1 + colb, lds + o0 + 8192);
  };

  // ds_read address bases; swizzle XOR value is constant per lane (fr&3)
  const int Xsw = (fr & 3) << 4;
  const int aA0 = ((wr * 128 + fr) * 64 + fq * 16) ^ Xsw;
  const int aB0 = ((wc * 64 + fr) * 64 + fq * 16) ^ Xsw;

  f32x4 acc[8][4] = {};

  // prologue: stage H0..H4, wait 2 halves landed, barrier
  for (int j = 0; j < 5; ++j) stage_j(j);
  asm volatile("s_waitcnt vmcnt(6)" ::: "memory");
  __builtin_amdgcn_s_barrier();

  for (int t = 0; t < 64; ++t) {
    const int b = t & 1;
#pragma unroll
    for (int p = 0; p < 4; ++p) {
      const int ks = p >> 1, mh = p & 1;
      const char* As_ = lds + (b * 4 + ks * 2) * 16384;
      const char* Bs_ = lds + (b * 4 + ks * 2 + 1) * 16384;
      short8 af[4], bv[4];
#pragma unroll
      for (int i = 0; i < 4; ++i)
        af[i] = *reinterpret_cast<const short8*>(As_ + (aA0 + mh * 4096 + i * 1024));
#pragma unroll
      for (int i = 0; i < 4; ++i)
        bv[i] = *reinterpret_cast<const short8*>(Bs_ + (aB0 + i * 1024));
      const int jst = 4 * t + p + 5;
      if (jst < 256) stage_j(jst);
      __builtin_amdgcn_s_barrier();
      asm volatile("s_waitcnt lgkmcnt(0)" ::: "memory");
      __builtin_amdgcn_sched_barrier(0);
      __builtin_amdgcn_s_setprio(1);
#pragma unroll
      for (int i = 0; i < 4; ++i)
#pragma unroll
        for (int j2 = 0; j2 < 4; ++j2)
          acc[mh * 4 + i][j2] = __builtin_amdgcn_mfma_f32_16x16x32_bf16(
              af[i], bv[j2], acc[mh * 4 + i][j2], 0, 0, 0);
      __builtin_amdgcn_s_setprio(0);
      __builtin_amdgcn_sched_barrier(0);
      if (p == 1) {
        if (t < 63) asm volatile("s_waitcnt vmcnt(6)" ::: "memory");
        else        asm volatile("s_waitcnt vmcnt(0)" ::: "memory");
      } else if (p == 3) {
        if (t < 62)       asm volatile("s_waitcnt vmcnt(6)" ::: "memory");
        else if (t == 62) asm volatile("s_waitcnt vmcnt(4)" ::: "memory");
      }
      __builtin_amdgcn_s_barrier();
    }
  }

  // epilogue: C/D layout col=lane&15, row=(lane>>4)*4+reg
  float* Cw = C + (size_t)(tm * 256 + wr * 128) * Ndim + tn * 256 + wc * 64;
#pragma unroll
  for (int mi = 0; mi < 8; ++mi)
#pragma unroll
    for (int nj = 0; nj < 4; ++nj)
#pragma unroll
      for (int r = 0; r < 4; ++r)
        Cw[(size_t)(mi * 16 + fq * 4 + r) * Ndim + nj * 16 + fr] = acc[mi][nj][r];
}

// ---------------- Fallback GEMM (f32 A, reg-staged) — only if ws too small -----
__global__ __launch_bounds__(256) void gemm_fb(
    const float* __restrict__ Af, const ushort_t* __restrict__ Bw,
    float* __restrict__ C) {
  constexpr int BM = 128, BN = 128, BK = 32;
  __shared__ ushort_t As[BM * BK];
  __shared__ ushort_t Bs[BN * BK];
  const int tid = threadIdx.x;
  const int w = tid >> 6, l = tid & 63;
  int bid = blockIdx.x;
  const int nwg = gridDim.x;
  if ((nwg & 7) == 0) { const int cpx = nwg >> 3; bid = (bid & 7) * cpx + (bid >> 3); }
  const int tn = bid & (Ndim / BN - 1);
  const int tm = bid >> 5;
  const int wr = w >> 1, wc = w & 1;
  const int fr = l & 15, fq = l >> 4;
  f32x4 acc[4][4] = {};
  const int arow = w * 16 + (l >> 2);
  const int acol = (l & 3) * 8;
  const long abase = (long)(tm * BM) * Kdim;
  const long bbase = (long)(tn * BN) * Kdim;
  for (int kk = 0; kk < Kdim; kk += BK) {
#pragma unroll
    for (int s = 0; s < 2; s++) {
      const ushort_t* gb = Bw + bbase + (long)(s * 64 + arow) * Kdim + kk + acol;
      GLOAD16(gb, &Bs[(s * 64 + w * 16) * BK]);
    }
#pragma unroll
    for (int s = 0; s < 2; s++) {
      const int r2 = s * 64 + (tid >> 2);
      const int c2 = (tid & 3) * 8;
      const float* gx = Af + abase + (long)r2 * Kdim + kk + c2;
      f32x4 v0 = *reinterpret_cast<const f32x4*>(gx);
      f32x4 v1 = *reinterpret_cast<const f32x4*>(gx + 4);
      u16x8 pk;
#pragma unroll
      for (int j = 0; j < 4; j++) { pk[j] = f2bf(v0[j]); pk[4 + j] = f2bf(v1[j]); }
      *reinterpret_cast<u16x8*>(&As[r2 * BK + c2]) = pk;
    }
    __syncthreads();
    short8 af[4], bfr[4];
#pragma unroll
    for (int i = 0; i < 4; i++)
      af[i] = *reinterpret_cast<const short8*>(&As[(wr * 64 + i * 16 + fr) * BK + fq * 8]);
#pragma unroll
    for (int i = 0; i < 4; i++)
      bfr[i] = *reinterpret_cast<const short8*>(&Bs[(wc * 64 + i * 16 + fr) * BK + fq * 8]);
#pragma unroll
    for (int i = 0; i < 4; i++)
#pragma unroll
      for (int j = 0; j < 4; j++)
        acc[i][j] = __builtin_amdgcn_mfma_f32_16x16x32_bf16(af[i], bfr[j], acc[i][j], 0, 0, 0);
    __syncthreads();
  }
  const long crow = (long)(tm * BM + wr * 64);
  const int ccol = tn * BN + wc * 64;
#pragma unroll
  for (int i = 0; i < 4; i++)
#pragma unroll
    for (int j = 0; j < 4; j++)
#pragma unroll
      for (int r = 0; r < 4; r++)
        C[(crow + i * 16 + fq * 4 + r) * (long)Ndim + ccol + j * 16 + fr] = acc[i][j][r];
}

extern "C" void kernel_launch(void* const* d_in, const int* in_sizes, int n_in,
                              void* d_out, int out_size, void* d_ws, size_t ws_size,
                              hipStream_t stream) {
  const float* x      = (const float*)d_in[0];
  const float* logits = (const float*)d_in[1];
  const float* u      = (const float*)d_in[2];
  const float* scales = (const float*)d_in[3];
  const int*   mask   = (const int*)d_in[4];
  float* out = (float*)d_out;

  ushort_t* W = (ushort_t*)d_ws;                       // [N][K] bf16, 32 MB
  const size_t wbytes = (size_t)Ndim * Kdim * 2;
  const size_t xbytes = (size_t)Mdim * Kdim * 2;

  wgen_kernel<<<(Ndim * (long)Kdim) / 1024, 256, 0, stream>>>(
      logits, u, scales, (const i32x4*)mask, W);

  if (ws_size >= wbytes + xbytes) {
    ushort_t* xb = (ushort_t*)((char*)d_ws + wbytes);  // [M][K] bf16, 64 MB
    xconv_kernel<<<(Mdim * (long)Kdim / 4) / 512, 256, 0, stream>>>(
        (const f32x4*)x, (u16x4*)xb);
    gemm8_kernel<<<(Mdim / 256) * (Ndim / 256), 512, 0, stream>>>(xb, W, out);
  } else {
    gemm_fb<<<(Mdim / 128) * (Ndim / 128), 256, 0, stream>>>(x, W, out);
  }
}